// Round 7
// baseline (175.266 us; speedup 1.0000x reference)
//
#include <hip/hip_runtime.h>

// Problem constants
#define BATCH 32
#define CIN   256
#define CR    8
#define HDIM  56
#define WDIM  56
#define HW    3136          // 56*56; HW % 4 == 0 -> 4-px lane groups never straddle images
#define COUT  44            // 8 z_norm + 36 interactions

#define TILE  256           // k1: pixels per block (lane owns 4 consecutive pixels)

// upper-triangular pair table for the 36 interaction channels
__device__ __constant__ const int PI36[36] =
    {0,0,0,0,0,0,0,0, 1,1,1,1,1,1,1, 2,2,2,2,2,2, 3,3,3,3,3, 4,4,4,4, 5,5,5, 6,6, 7};
__device__ __constant__ const int PJ36[36] =
    {0,1,2,3,4,5,6,7, 1,2,3,4,5,6,7, 2,3,4,5,6,7, 3,4,5,6,7, 4,5,6,7, 5,6,7, 6,7, 7};

// ---------------------------------------------------------------------------
// Kernel 1: 1x1 conv reduce (256->8) + BN + ReLU.
// REQUEST-WIDTH EXPERIMENT (m13-proven width): every dword variant pinned at
// ~2.4-2.5 TB/s independent of occupancy/pipelining -> hypothesis: the vmem
// path sustains ~fixed requests/sec, so bytes-per-request sets BW. This
// version issues dwordx4 (16B/lane, 1KB/wave-request), the exact width that
// measured 6.29 TB/s in the m13 copy microbenchmark.
//   Block = 512 threads = 8 waves over a 256-px tile; wave w reduces cin
//   [32w,32w+32) with a 2-buffer 4-deep float4 pipeline (4-8KB in flight per
//   wave). Grid 392 blocks, 2 blocks/CU (64KB LDS) = 16 waves/CU -> ~64KB
//   in flight per CU >> ~9KB needed for peak HBM BW.
//   LDS combine layout pacc[wave][ch][px]: the b128 partial writes are
//   stride-16B across lanes (<=2-way bank aliasing, free per m136) -- a
//   [px][ch] layout at 16B/lane would be a 32-way conflict.
// z written channels-last [pixel][8] (32B/pixel) for kernel 2.
// ---------------------------------------------------------------------------
__global__ __launch_bounds__(512, 4) void k1_reduce_bn_relu(
    const float* __restrict__ x, const float* __restrict__ wr,
    const float* __restrict__ gamma, const float* __restrict__ beta,
    const float* __restrict__ mean, const float* __restrict__ var,
    float* __restrict__ z)
{
    const int tid  = threadIdx.x;
    const int lane = tid & 63;
    const int wv   = __builtin_amdgcn_readfirstlane(tid >> 6);   // 0..7
    const int px0  = blockIdx.x * TILE;          // block's first pixel
    const int gp   = px0 + 4 * lane;             // lane's 4-pixel group
    const int b    = gp / HW;                    // group never straddles images
    const int p    = gp - b * HW;
    const int cin0 = wv * 32;

    const float* __restrict__ xq =
        x + (size_t)b * CIN * HW + (size_t)cin0 * HW + p;

    float acc[4][CR];                            // [px in group][channel]
#pragma unroll
    for (int q = 0; q < 4; ++q)
#pragma unroll
        for (int c = 0; c < CR; ++c) acc[q][c] = 0.f;

    float4 xa[4], xb[4];
    auto loadx = [&](float4 (&arr)[4], int base) {
#pragma unroll
        for (int j = 0; j < 4; ++j)
            arr[j] = *reinterpret_cast<const float4*>(
                         xq + (size_t)(base + j) * HW);   // 1KB/wave request
    };
    auto consume = [&](const float4 (&arr)[4], int base) {
#pragma unroll
        for (int j = 0; j < 4; ++j) {
            const int cin = cin0 + base + j;              // wave-uniform
            const float px4[4] = {arr[j].x, arr[j].y, arr[j].z, arr[j].w};
#pragma unroll
            for (int c = 0; c < CR; ++c) {
                const float wgt = wr[c * CIN + cin];      // scalar load
#pragma unroll
                for (int q = 0; q < 4; ++q)
                    acc[q][c] = fmaf(px4[q], wgt, acc[q][c]);
            }
        }
    };

    loadx(xa, 0);
    loadx(xb, 4);            // 8 float4 (8KB/wave) in flight
#pragma unroll
    for (int k0 = 0; k0 < 32; k0 += 8) {
        consume(xa, k0);
        if (k0 + 8  < 32) loadx(xa, k0 + 8);   // issued while xb in flight
        consume(xb, k0 + 4);
        if (k0 + 12 < 32) loadx(xb, k0 + 12);
    }

    // cross-wave reduction of the 8 cin-group partials.
    // Layout [wv][c][px]: write = b128 at stride 16B across lanes (conflict-
    // free); read = consecutive 4B across lanes (conflict-free).
    __shared__ float pacc[8][CR][TILE];          // 64 KB
#pragma unroll
    for (int c = 0; c < CR; ++c)
        *reinterpret_cast<float4*>(&pacc[wv][c][4 * lane]) =
            make_float4(acc[0][c], acc[1][c], acc[2][c], acc[3][c]);
    __syncthreads();

    // 2048 outputs (256 px * 8 ch), 512 threads -> 4 each. Thread t owns
    // channel c = t>>6 and pixels {t&63} + 64k. BN params uniform per thread.
    const int c   = tid >> 6;                    // 0..7
    const int pxb = tid & 63;
    const float inv = gamma[c] / sqrtf(var[c] + 1e-5f);
    const float sh  = beta[c] - mean[c] * inv;
#pragma unroll
    for (int k = 0; k < 4; ++k) {
        const int px = pxb + 64 * k;
        float s = 0.f;
#pragma unroll
        for (int w = 0; w < 8; ++w) s += pacc[w][c][px];
        z[(size_t)(px0 + px) * CR + c] = fmaxf(fmaf(s, inv, sh), 0.f);
    }
}

// ---------------------------------------------------------------------------
// Kernel 2 (UNCHANGED from R6 -- frozen so R7-R6 isolates Delta-k1):
// depthwise 3x3 * scale + L2 norms + 36 pairwise products -> 44 channels.
// 256-thread block = 4 waves over the same 64 pixels; each wave redundantly
// computes conv+norms and writes an 11-channel slice of the outputs.
// ---------------------------------------------------------------------------
__global__ __launch_bounds__(256) void k2_dw_norm_inter(
    const float* __restrict__ z, const float* __restrict__ wdw,
    const float* __restrict__ scale, float* __restrict__ out)
{
    const int lane = threadIdx.x & 63;
    const int wv   = __builtin_amdgcn_readfirstlane(threadIdx.x >> 6); // 0..3
    const int t = blockIdx.x * 64 + lane;          // global pixel id
    const int b = t / HW;
    const int p = t - b * HW;
    const int h = p / WDIM;
    const int w = p - h * WDIM;

    const float* __restrict__ zimg = z + (size_t)b * HW * CR;

    // issue all 9 tap loads first (static reg indices, one waitcnt)
    float4 n0[9], n1[9];
    float  mk[9];
#pragma unroll
    for (int dy = -1; dy <= 1; ++dy) {
#pragma unroll
        for (int dx = -1; dx <= 1; ++dx) {
            const int k  = (dy + 1) * 3 + (dx + 1);
            const int hh = h + dy, ww = w + dx;
            const bool ok = (hh >= 0) & (hh < HDIM) & (ww >= 0) & (ww < WDIM);
            const int hc = min(max(hh, 0), HDIM - 1);
            const int wc = min(max(ww, 0), WDIM - 1);
            mk[k] = ok ? 1.0f : 0.0f;
            const float* zn = zimg + (size_t)(hc * WDIM + wc) * CR;
            n0[k] = reinterpret_cast<const float4*>(zn)[0];
            n1[k] = reinterpret_cast<const float4*>(zn)[1];
        }
    }

    const float zc[CR] = {n0[4].x, n0[4].y, n0[4].z, n0[4].w,
                          n1[4].x, n1[4].y, n1[4].z, n1[4].w};

    float tw[CR];
#pragma unroll
    for (int c = 0; c < CR; ++c) tw[c] = 0.f;
#pragma unroll
    for (int k = 0; k < 9; ++k) {
        const float nv[CR] = {n0[k].x, n0[k].y, n0[k].z, n0[k].w,
                              n1[k].x, n1[k].y, n1[k].z, n1[k].w};
#pragma unroll
        for (int c = 0; c < CR; ++c)
            tw[c] = fmaf(nv[c] * mk[k], wdw[c * 9 + k], tw[c]);
    }

    float s1 = 0.f, s2 = 0.f;
#pragma unroll
    for (int c = 0; c < CR; ++c) {
        tw[c] *= scale[c];
        s1 = fmaf(zc[c], zc[c], s1);
        s2 = fmaf(tw[c], tw[c], s2);
    }
    const float r1 = 1.0f / fmaxf(sqrtf(s1), 1e-6f);
    const float r2 = 1.0f / fmaxf(sqrtf(s2), 1e-6f);

    float a[CR], tb[CR];
#pragma unroll
    for (int c = 0; c < CR; ++c) { a[c] = zc[c] * r1; tb[c] = tw[c] * r2; }

    // this wave's 11-channel slice of the 44 outputs (compile-time idx)
    float* op = out + (size_t)b * COUT * HW + p;
#pragma unroll
    for (int c = 0; c < COUT; ++c) {
        if ((c / 11) == wv) {
            const float val = (c < CR) ? a[c]
                                       : a[PI36[c - CR]] * tb[PJ36[c - CR]];
            op[(size_t)c * HW] = val;
        }
    }
}

extern "C" void kernel_launch(void* const* d_in, const int* in_sizes, int n_in,
                              void* d_out, int out_size, void* d_ws, size_t ws_size,
                              hipStream_t stream) {
    const float* x     = (const float*)d_in[0];
    const float* wr    = (const float*)d_in[1];
    const float* gamma = (const float*)d_in[2];
    const float* beta  = (const float*)d_in[3];
    const float* mean  = (const float*)d_in[4];
    const float* var   = (const float*)d_in[5];
    const float* wdw   = (const float*)d_in[6];
    const float* scale = (const float*)d_in[7];
    float* out = (float*)d_out;
    float* z   = (float*)d_ws;   // BATCH*HW*CR floats = 3.21 MB, channels-last

    const int npix = BATCH * HW;              // 100352
    k1_reduce_bn_relu<<<npix / TILE, 512, 0, stream>>>(x, wr, gamma, beta, mean, var, z);
    k2_dw_norm_inter<<<npix / 64, 256, 0, stream>>>(z, wdw, scale, out);
}